// Round 19
// baseline (675.920 us; speedup 1.0000x reference)
//
#include <hip/hip_runtime.h>
#include <stdint.h>

#define NE 131072
#define SBCH 32768          // chunk (L3-safe, R13-verified)

typedef __attribute__((ext_vector_type(8))) short bf16x8;
typedef __attribute__((ext_vector_type(4))) float f32x4;

static __device__ __forceinline__ unsigned short f2bf(float f) {
  unsigned u = __float_as_uint(f);
  u += 0x7FFF + ((u >> 16) & 1);   // round-to-nearest-even
  return (unsigned short)(u >> 16);
}
static __device__ __forceinline__ float bf2f(unsigned short h) {
  return __uint_as_float((unsigned)h << 16);
}
static __device__ __forceinline__ void gload_lds16(const void* g, void* l) {
  __builtin_amdgcn_global_load_lds(
      (const __attribute__((address_space(1))) unsigned*)g,
      (__attribute__((address_space(3))) unsigned*)l, 16, 0, 0);
}

// Merged prep (verified R18): y 0-11 = weight transpose+cvt; y==12 = x
// relu/cvt; y==13 = per-(chunk,pair) compaction.
__global__ void prep_all(const float* __restrict__ W0, const float* __restrict__ W1,
                         const float* __restrict__ W2, const float* __restrict__ SW0,
                         const float* __restrict__ SW1, const float* __restrict__ SW2,
                         unsigned short* W0t, unsigned short* W1t,
                         unsigned short* W2t, unsigned short* SW0t,
                         unsigned short* SW1t, unsigned short* SW2b,
                         const float4* __restrict__ x, ushort4* __restrict__ xb,
                         const int* __restrict__ y, const int* __restrict__ pairs,
                         int* __restrict__ idxL, int* __restrict__ posA,
                         int* __restrict__ cnts) {
  const int u = blockIdx.y;
  if (u == 12) {                       // ---- relu_cvt_x ----
    const int tot = NE * 64 / 4;
    for (int i = blockIdx.x * 256 + threadIdx.x; i < tot; i += 256 * 256) {
      float4 v = x[i];
      ushort4 o;
      o.x = f2bf(fmaxf(v.x, 0.f));
      o.y = f2bf(fmaxf(v.y, 0.f));
      o.z = f2bf(fmaxf(v.z, 0.f));
      o.w = f2bf(fmaxf(v.w, 0.f));
      xb[i] = o;
    }
    return;
  }
  if (u == 13) {                       // ---- build_idx ----
    if (blockIdx.x >= 12) return;
    const int c = blockIdx.x & 3, p = blockIdx.x >> 2;
    const int la = pairs[p * 2], lb = pairs[p * 2 + 1];
    const long r0 = (long)c * SBCH;
    const long cb = r0;
    __shared__ int wbase[4];
    __shared__ int running;
    if (threadIdx.x == 0) running = 0;
    __syncthreads();
    const int lane = threadIdx.x & 63, wv = threadIdx.x >> 6;
    for (int it = 0; it < SBCH / 256; ++it) {
      const int r = it * 256 + threadIdx.x;
      const int yv = y[r0 + r];
      const bool act = (yv == la) || (yv == lb);
      const unsigned long long m = __ballot(act);
      const int rank = __popcll(m & ((1ull << lane) - 1));
      if (lane == 0) wbase[wv] = __popcll(m);
      __syncthreads();
      int wb = 0;
#pragma unroll
      for (int w = 0; w < 4; ++w) wb += (w < wv) ? wbase[w] : 0;
      const int tot = wbase[0] + wbase[1] + wbase[2] + wbase[3];
      if (act) {
        const int posi = running + wb + rank;
        idxL[(long)p * NE + cb + posi] = r;
        posA[(long)p * NE + r0 + r] = (int)(cb + posi);
      } else {
        posA[(long)p * NE + r0 + r] = -1;
      }
      __syncthreads();
      if (threadIdx.x == 0) running += tot;
      __syncthreads();
    }
    const int cnt = running;
    if (threadIdx.x == 0) cnts[c * 3 + p] = cnt;
    const int padded = (cnt + 255) & ~255;
    const int last = (cnt > 0) ? idxL[(long)p * NE + cb + cnt - 1] : 0;
    for (int i = cnt + threadIdx.x; i < padded; i += 256)
      idxL[(long)p * NE + cb + i] = last;
    return;
  }
  // ---- weight transpose+cvt: dst[n][k] = bf16(src[k][n]) ----
  __shared__ float tile[32][33];
  const float* src; unsigned short* dst; int K, Nc;
  if (u == 0)      { src = W0;  dst = W0t;  K = 64;  Nc = 512; }
  else if (u == 1) { src = W1;  dst = W1t;  K = 512; Nc = 512; }
  else if (u == 2) { src = W2;  dst = W2t;  K = 512; Nc = 512; }
  else if (u < 6)  { int p = u - 3; src = SW0 + (long)p * 512 * 512; dst = SW0t + (long)p * 512 * 512; K = 512; Nc = 512; }
  else if (u < 9)  { int p = u - 6; src = SW1 + (long)p * 512 * 256; dst = SW1t + (long)p * 256 * 512; K = 512; Nc = 256; }
  else             { int p = u - 9; src = SW2 + (long)p * 256;       dst = SW2b + (long)p * 256;       K = 256; Nc = 1; }
  const int tkn = K >> 5;
  const int tk = blockIdx.x % tkn, tn = blockIdx.x / tkn;
  if (tn >= ((Nc + 31) >> 5)) return;
  const int k0 = tk * 32, n0 = tn * 32;
  const int tx = threadIdx.x & 31, ty = threadIdx.x >> 5;
  if (n0 + tx < Nc)
#pragma unroll
    for (int j = 0; j < 4; ++j)
      tile[ty * 4 + j][tx] = src[(long)(k0 + ty * 4 + j) * Nc + n0 + tx];
  __syncthreads();
#pragma unroll
  for (int j = 0; j < 4; ++j) {
    int n = n0 + ty * 4 + j;
    if (n < Nc) dst[(long)n * K + k0 + tx] = f2bf(tile[tx][ty * 4 + j]);
  }
}

// gemmT (R18-verified): R9 schedule (3-ring 72KB, 2 blk/CU, counted
// vmcnt(3), involution addressing 0-conflict), BM=128 x BN=256, 8 waves
// 2M x 4N (64x64 wave-tile). NT store on outF. Optional A-row gather +
// cnts early-exit. NEW: fully fused head (w2 path) — computes sigmoid/
// ratio and scatter-writes dense outputs via idxL inverse map; masked
// entries pre-zeroed by hipMemsetAsync (head_final dispatch eliminated).
__global__ __launch_bounds__(512, 4) void gemmT(
    const unsigned short* __restrict__ A, long aZ,
    const unsigned short* __restrict__ Bt, long bZ,
    const float* __restrict__ bias, long biasZ,
    float* __restrict__ outF,
    unsigned short* __restrict__ outA, long cZ,
    int K, int Nc,
    const unsigned short* __restrict__ w2, long w2Z, int r0,
    const int* __restrict__ aIdx, long aIdxZ,
    const int* __restrict__ cnts,
    const float* __restrict__ Sb2v, const int* __restrict__ invIdx,
    float* __restrict__ goR, float* __restrict__ goS,
    float* __restrict__ goM) {
  __shared__ unsigned short lds[3 * 12288];   // 72 KB: per buf A 8KB + B 16KB
  __shared__ float part[4][128];
  const int z = blockIdx.z;
  const long brow = (long)blockIdx.x * 128;
  int cpz = 0;
  if (cnts) {
    cpz = cnts[z];
    if ((int)brow >= ((cpz + 255) & ~255)) return;
  }
  A += (long)z * aZ;
  Bt += (long)z * bZ;
  bias += (long)z * biasZ;
  if (outA) outA += (long)z * cZ;
  if (w2) w2 += (long)z * w2Z;
  if (aIdx) aIdx += (long)z * aIdxZ;

  const int tid = threadIdx.x, wave = tid >> 6, lane = tid & 63;
  const int wm = wave >> 2, wn = wave & 3;   // 2M x 4N
  const int lr = lane & 15, lh = lane >> 4;
  const int bcol = blockIdx.y * 256;
  const int nk = K >> 5;
  const int axr = (lh ^ ((lr >> 1) & 3)) * 8;   // involution read col (elems)

  // A source row (K-tile-invariant; 1 stage-load/thread)
  const int arL = tid >> 2;                     // LDS-local A row 0..127
  const int arow = aIdx ? aIdx[brow + arL] : (int)(brow + arL);

  f32x4 acc[4][4];
#pragma unroll
  for (int m = 0; m < 4; ++m)
#pragma unroll
    for (int n = 0; n < 4; ++n) acc[m][n] = (f32x4){0.f, 0.f, 0.f, 0.f};

  auto STAGE = [&](int t) {
    if (t >= nk) return;
    unsigned short* dst = &lds[(t % 3) * 12288];
    const int k0 = t << 5;
    {                                           // A: 512 chunks, 1/thread
      const int c = tid;
      const int r = c >> 2;
      const int kc = (c & 3) ^ ((r >> 1) & 3);
      gload_lds16(A + (long)arow * K + k0 + kc * 8, &dst[(wave * 64) * 8]);
    }
#pragma unroll
    for (int i = 0; i < 2; ++i) {               // B: 1024 chunks, 2/thread
      const int cb = i * 512 + wave * 64;
      const int c = cb + lane;
      const int r = c >> 2;
      const int kc = (c & 3) ^ ((r >> 1) & 3);
      gload_lds16(Bt + (long)(bcol + r) * K + k0 + kc * 8,
                  &dst[(512 + cb) * 8]);
    }
  };

  STAGE(0);
  STAGE(1);

  for (int t = 0; t < nk; ++t) {
    if (t < nk - 1)
      asm volatile("s_waitcnt vmcnt(3)" ::: "memory");
    else
      asm volatile("s_waitcnt vmcnt(0)" ::: "memory");
    __builtin_amdgcn_s_barrier();
    __builtin_amdgcn_sched_barrier(0);
    const unsigned short* buf = &lds[(t % 3) * 12288];
    bf16x8 a[4], b[4];
#pragma unroll
    for (int m = 0; m < 4; ++m)
      a[m] = *(const bf16x8*)&buf[(wm * 64 + m * 16 + lr) * 32 + axr];
#pragma unroll
    for (int n = 0; n < 4; ++n)
      b[n] = *(const bf16x8*)&buf[512 * 8 + (wn * 64 + n * 16 + lr) * 32 + axr];
    STAGE(t + 2);
    __builtin_amdgcn_s_setprio(1);
#pragma unroll
    for (int m = 0; m < 4; ++m)
#pragma unroll
      for (int n = 0; n < 4; ++n)
        acc[m][n] =
            __builtin_amdgcn_mfma_f32_16x16x32_bf16(a[m], b[n], acc[m][n], 0, 0, 0);
    __builtin_amdgcn_s_setprio(0);
  }

  float bv[4];
#pragma unroll
  for (int n = 0; n < 4; ++n) bv[n] = bias[bcol + wn * 64 + n * 16 + lr];

  if (!w2) {
#pragma unroll
    for (int m = 0; m < 4; ++m) {
#pragma unroll
      for (int r = 0; r < 4; ++r) {
        long e = brow + wm * 64 + m * 16 + lh * 4 + r;
#pragma unroll
        for (int n = 0; n < 4; ++n) {
          int oc = bcol + wn * 64 + n * 16 + lr;
          float v = acc[m][n][r] + bv[n];
          // repr written once, never re-read: NT store protects L3 (R18).
          if (outF) __builtin_nontemporal_store(v, &outF[e * Nc + oc]);
          if (outA) outA[e * Nc + oc] = f2bf(fmaxf(v, 0.f));
        }
      }
    }
  } else {
    // fused head: logit partials per wn group, then sigmoid/ratio and
    // scatter to dense outputs via inverse compact map (idxL).
    float w2v[4];
#pragma unroll
    for (int n = 0; n < 4; ++n) w2v[n] = bf2f(w2[wn * 64 + n * 16 + lr]);
#pragma unroll
    for (int m = 0; m < 4; ++m) {
#pragma unroll
      for (int r = 0; r < 4; ++r) {
        float s = 0.f;
#pragma unroll
        for (int n = 0; n < 4; ++n)
          s += fmaxf(acc[m][n][r] + bv[n], 0.f) * w2v[n];
#pragma unroll
        for (int off = 1; off < 16; off <<= 1) s += __shfl_xor(s, off);
        if (lr == 0) part[wn][wm * 64 + m * 16 + lh * 4 + r] = s;
      }
    }
    __syncthreads();
    if (tid < 128) {
      const int posL = (int)brow + tid;          // within-chunk compact pos
      if (posL < cpz) {                          // skip padded dups
        float logit = part[0][tid] + part[1][tid] + part[2][tid] +
                      part[3][tid] + Sb2v[z];
        float s = 1.f / (1.f + expf(-logit));
        s = fmaxf(s, 1e-9f);
        float rr = (1.f - s) / s;
        const long orig = (long)r0 + invIdx[(long)z * NE + r0 + posL];
        goR[(long)z * NE + orig] = rr;
        goS[(long)z * NE + orig] = s;
        goM[(long)z * NE + orig] = 1.f;
      }
    }
  }
}

extern "C" void kernel_launch(void* const* d_in, const int* in_sizes, int n_in,
                              void* d_out, int out_size, void* d_ws, size_t ws_size,
                              hipStream_t stream) {
  const float* x   = (const float*)d_in[0];
  const int*   y   = (const int*)d_in[1];
  const int*   prs = (const int*)d_in[2];
  const float* W0  = (const float*)d_in[3];
  const float* b0  = (const float*)d_in[4];
  const float* W1  = (const float*)d_in[5];
  const float* b1  = (const float*)d_in[6];
  const float* W2  = (const float*)d_in[7];
  const float* b2  = (const float*)d_in[8];
  const float* SW0 = (const float*)d_in[9];
  const float* Sb0 = (const float*)d_in[10];
  const float* SW1 = (const float*)d_in[11];
  const float* Sb1 = (const float*)d_in[12];
  const float* SW2 = (const float*)d_in[13];
  const float* Sb2 = (const float*)d_in[14];

  uint8_t* ws = (uint8_t*)d_ws;
  size_t off = 0;
  auto take = [&](size_t bytes) -> void* {
    void* ptr = ws + off;
    off = (off + bytes + 255) & ~(size_t)255;
    return ptr;
  };
  unsigned short* W0t  = (unsigned short*)take((size_t)64 * 512 * 2);
  unsigned short* W1t  = (unsigned short*)take((size_t)512 * 512 * 2);
  unsigned short* W2t  = (unsigned short*)take((size_t)512 * 512 * 2);
  unsigned short* SW0t = (unsigned short*)take((size_t)3 * 512 * 512 * 2);
  unsigned short* SW1t = (unsigned short*)take((size_t)3 * 256 * 512 * 2);
  unsigned short* SW2b = (unsigned short*)take((size_t)3 * 256 * 2);
  unsigned short* Xb   = (unsigned short*)take((size_t)NE * 64 * 2);
  int*            idxL = (int*)take((size_t)3 * NE * 4);
  int*            posA = (int*)take((size_t)3 * NE * 4);
  int*            cnts = (int*)take((size_t)64 * 4);

  // chunk 32768: R13-verified L3-resident optimum (R15/R17: larger thrash).
  const long chunk = SBCH;
  const int nchunks = (int)(NE / chunk);

  unsigned short* T0   = (unsigned short*)take((size_t)chunk * 512 * 2);
  unsigned short* T1   = (unsigned short*)take((size_t)chunk * 512 * 2);
  unsigned short* bufR = (unsigned short*)take((size_t)chunk * 512 * 2);
  unsigned short* H3   = (unsigned short*)take((size_t)3 * chunk * 512 * 2);

  float* out   = (float*)d_out;
  float* outRe = out;
  float* outR  = out + (size_t)NE * 512;
  float* outS  = outR + (size_t)3 * NE;
  float* outM  = outS + (size_t)3 * NE;

  prep_all<<<dim3(256, 14), 256, 0, stream>>>(
      W0, W1, W2, SW0, SW1, SW2, W0t, W1t, W2t, SW0t, SW1t, SW2b,
      (const float4*)x, (ushort4*)Xb, y, prs, idxL, posA, cnts);
  // zero the mask-dependent outputs (outR/outS/outM = 9*NE floats);
  // active entries are overwritten by the fused SW1 head.
  hipMemsetAsync(outR, 0, (size_t)9 * NE * 4, stream);

  for (int c = 0; c < nchunks; ++c) {
    const long r0 = (long)c * chunk;
    // trunk: Xb -> T0 -> T1 -> (repr fp32 NT, bufR bf16)
    gemmT<<<dim3(chunk / 128, 2, 1), 512, 0, stream>>>(
        Xb + r0 * 64, 0, W0t, 0, b0, 0, nullptr, T0, 0, 64, 512,
        nullptr, 0, 0, nullptr, 0, nullptr,
        nullptr, nullptr, nullptr, nullptr, nullptr);
    gemmT<<<dim3(chunk / 128, 2, 1), 512, 0, stream>>>(
        T0, 0, W1t, 0, b1, 0, nullptr, T1, 0, 512, 512,
        nullptr, 0, 0, nullptr, 0, nullptr,
        nullptr, nullptr, nullptr, nullptr, nullptr);
    gemmT<<<dim3(chunk / 128, 2, 1), 512, 0, stream>>>(
        T1, 0, W2t, 0, b2, 0, outRe + r0 * 512, bufR, 0, 512, 512,
        nullptr, 0, 0, nullptr, 0, nullptr,
        nullptr, nullptr, nullptr, nullptr, nullptr);
    // SW0 batched over p, compacted rows: bufR -> H3[p]
    gemmT<<<dim3(chunk / 128, 2, 3), 512, 0, stream>>>(
        bufR, 0, SW0t, (long)512 * 512, Sb0, 512, nullptr,
        H3, (long)chunk * 512, 512, 512,
        nullptr, 0, 0, idxL + r0, NE, cnts + c * 3,
        nullptr, nullptr, nullptr, nullptr, nullptr);
    // SW1 + fully fused head on compact rows (Nc=256, y=1): writes
    // outR/outS/outM directly via idxL inverse map.
    gemmT<<<dim3(chunk / 128, 1, 3), 512, 0, stream>>>(
        H3, (long)chunk * 512, SW1t, (long)256 * 512, Sb1, 256, nullptr,
        nullptr, 0, 512, 256,
        SW2b, 256, (int)r0, nullptr, 0, cnts + c * 3,
        Sb2, idxL, outR, outS, outM);
  }
}

// Round 20
// 671.261 us; speedup vs baseline: 1.0069x; 1.0069x over previous
//
#include <hip/hip_runtime.h>
#include <stdint.h>

#define NE 131072
#define SBCH 32768          // chunk (L3-safe, R13-verified)

typedef __attribute__((ext_vector_type(8))) short bf16x8;
typedef __attribute__((ext_vector_type(4))) float f32x4;

static __device__ __forceinline__ unsigned short f2bf(float f) {
  unsigned u = __float_as_uint(f);
  u += 0x7FFF + ((u >> 16) & 1);   // round-to-nearest-even
  return (unsigned short)(u >> 16);
}
static __device__ __forceinline__ float bf2f(unsigned short h) {
  return __uint_as_float((unsigned)h << 16);
}
static __device__ __forceinline__ void gload_lds16(const void* g, void* l) {
  __builtin_amdgcn_global_load_lds(
      (const __attribute__((address_space(1))) unsigned*)g,
      (__attribute__((address_space(3))) unsigned*)l, 16, 0, 0);
}

// Merged prep (verified R18/R19): y 0-11 weight transpose+cvt; y==12 x
// relu/cvt; y==13 per-(chunk,pair) compaction.
__global__ void prep_all(const float* __restrict__ W0, const float* __restrict__ W1,
                         const float* __restrict__ W2, const float* __restrict__ SW0,
                         const float* __restrict__ SW1, const float* __restrict__ SW2,
                         unsigned short* W0t, unsigned short* W1t,
                         unsigned short* W2t, unsigned short* SW0t,
                         unsigned short* SW1t, unsigned short* SW2b,
                         const float4* __restrict__ x, ushort4* __restrict__ xb,
                         const int* __restrict__ y, const int* __restrict__ pairs,
                         int* __restrict__ idxL, int* __restrict__ posA,
                         int* __restrict__ cnts) {
  const int u = blockIdx.y;
  if (u == 12) {
    const int tot = NE * 64 / 4;
    for (int i = blockIdx.x * 256 + threadIdx.x; i < tot; i += 256 * 256) {
      float4 v = x[i];
      ushort4 o;
      o.x = f2bf(fmaxf(v.x, 0.f));
      o.y = f2bf(fmaxf(v.y, 0.f));
      o.z = f2bf(fmaxf(v.z, 0.f));
      o.w = f2bf(fmaxf(v.w, 0.f));
      xb[i] = o;
    }
    return;
  }
  if (u == 13) {
    if (blockIdx.x >= 12) return;
    const int c = blockIdx.x & 3, p = blockIdx.x >> 2;
    const int la = pairs[p * 2], lb = pairs[p * 2 + 1];
    const long r0 = (long)c * SBCH;
    const long cb = r0;
    __shared__ int wbase[4];
    __shared__ int running;
    if (threadIdx.x == 0) running = 0;
    __syncthreads();
    const int lane = threadIdx.x & 63, wv = threadIdx.x >> 6;
    for (int it = 0; it < SBCH / 256; ++it) {
      const int r = it * 256 + threadIdx.x;
      const int yv = y[r0 + r];
      const bool act = (yv == la) || (yv == lb);
      const unsigned long long m = __ballot(act);
      const int rank = __popcll(m & ((1ull << lane) - 1));
      if (lane == 0) wbase[wv] = __popcll(m);
      __syncthreads();
      int wb = 0;
#pragma unroll
      for (int w = 0; w < 4; ++w) wb += (w < wv) ? wbase[w] : 0;
      const int tot = wbase[0] + wbase[1] + wbase[2] + wbase[3];
      if (act) {
        const int posi = running + wb + rank;
        idxL[(long)p * NE + cb + posi] = r;
        posA[(long)p * NE + r0 + r] = (int)(cb + posi);
      } else {
        posA[(long)p * NE + r0 + r] = -1;
      }
      __syncthreads();
      if (threadIdx.x == 0) running += tot;
      __syncthreads();
    }
    const int cnt = running;
    if (threadIdx.x == 0) cnts[c * 3 + p] = cnt;
    const int padded = (cnt + 255) & ~255;
    const int last = (cnt > 0) ? idxL[(long)p * NE + cb + cnt - 1] : 0;
    for (int i = cnt + threadIdx.x; i < padded; i += 256)
      idxL[(long)p * NE + cb + i] = last;
    return;
  }
  __shared__ float tile[32][33];
  const float* src; unsigned short* dst; int K, Nc;
  if (u == 0)      { src = W0;  dst = W0t;  K = 64;  Nc = 512; }
  else if (u == 1) { src = W1;  dst = W1t;  K = 512; Nc = 512; }
  else if (u == 2) { src = W2;  dst = W2t;  K = 512; Nc = 512; }
  else if (u < 6)  { int p = u - 3; src = SW0 + (long)p * 512 * 512; dst = SW0t + (long)p * 512 * 512; K = 512; Nc = 512; }
  else if (u < 9)  { int p = u - 6; src = SW1 + (long)p * 512 * 256; dst = SW1t + (long)p * 256 * 512; K = 512; Nc = 256; }
  else             { int p = u - 9; src = SW2 + (long)p * 256;       dst = SW2b + (long)p * 256;       K = 256; Nc = 1; }
  const int tkn = K >> 5;
  const int tk = blockIdx.x % tkn, tn = blockIdx.x / tkn;
  if (tn >= ((Nc + 31) >> 5)) return;
  const int k0 = tk * 32, n0 = tn * 32;
  const int tx = threadIdx.x & 31, ty = threadIdx.x >> 5;
  if (n0 + tx < Nc)
#pragma unroll
    for (int j = 0; j < 4; ++j)
      tile[ty * 4 + j][tx] = src[(long)(k0 + ty * 4 + j) * Nc + n0 + tx];
  __syncthreads();
#pragma unroll
  for (int j = 0; j < 4; ++j) {
    int n = n0 + ty * 4 + j;
    if (n < Nc) dst[(long)n * K + k0 + tx] = f2bf(tile[tx][ty * 4 + j]);
  }
}

// Parameter block for one GEMM stage (R19 gemmT semantics).
struct GArgs {
  const unsigned short* A; long aZ;
  const unsigned short* Bt; long bZ;
  const float* bias; long biasZ;
  float* outF;
  unsigned short* outA; long cZ;
  int K, Nc;
  const unsigned short* w2; long w2Z; int r0;
  const int* aIdx; long aIdxZ;
  const int* cnts;
  const float* Sb2v; const int* invIdx;
  float* goR; float* goS; float* goM;
  int gx, gy, gz;
};

// R19-verified gemmT body (byte-identical logic), block coords as params.
static __device__ __forceinline__ void gemm_body(
    unsigned short* lds, float* part, int bx, int by, int z, const GArgs& G) {
  const long brow = (long)bx * 128;
  int cpz = 0;
  if (G.cnts) {
    cpz = G.cnts[z];
    if ((int)brow >= ((cpz + 255) & ~255)) return;
  }
  const unsigned short* A = G.A + (long)z * G.aZ;
  const unsigned short* Bt = G.Bt + (long)z * G.bZ;
  const float* bias = G.bias + (long)z * G.biasZ;
  unsigned short* outA = G.outA ? G.outA + (long)z * G.cZ : nullptr;
  const unsigned short* w2 = G.w2 ? G.w2 + (long)z * G.w2Z : nullptr;
  const int* aIdx = G.aIdx ? G.aIdx + (long)z * G.aIdxZ : nullptr;
  const int K = G.K, Nc = G.Nc;

  const int tid = threadIdx.x, wave = tid >> 6, lane = tid & 63;
  const int wm = wave >> 2, wn = wave & 3;
  const int lr = lane & 15, lh = lane >> 4;
  const int bcol = by * 256;
  const int nk = K >> 5;
  const int axr = (lh ^ ((lr >> 1) & 3)) * 8;

  const int arL = tid >> 2;
  const int arow = aIdx ? aIdx[brow + arL] : (int)(brow + arL);

  f32x4 acc[4][4];
#pragma unroll
  for (int m = 0; m < 4; ++m)
#pragma unroll
    for (int n = 0; n < 4; ++n) acc[m][n] = (f32x4){0.f, 0.f, 0.f, 0.f};

  auto STAGE = [&](int t) {
    if (t >= nk) return;
    unsigned short* dst = &lds[(t % 3) * 12288];
    const int k0 = t << 5;
    {
      const int c = tid;
      const int r = c >> 2;
      const int kc = (c & 3) ^ ((r >> 1) & 3);
      gload_lds16(A + (long)arow * K + k0 + kc * 8, &dst[(wave * 64) * 8]);
    }
#pragma unroll
    for (int i = 0; i < 2; ++i) {
      const int cb = i * 512 + wave * 64;
      const int c = cb + lane;
      const int r = c >> 2;
      const int kc = (c & 3) ^ ((r >> 1) & 3);
      gload_lds16(Bt + (long)(bcol + r) * K + k0 + kc * 8,
                  &dst[(512 + cb) * 8]);
    }
  };

  STAGE(0);
  STAGE(1);

  for (int t = 0; t < nk; ++t) {
    if (t < nk - 1)
      asm volatile("s_waitcnt vmcnt(3)" ::: "memory");
    else
      asm volatile("s_waitcnt vmcnt(0)" ::: "memory");
    __builtin_amdgcn_s_barrier();
    __builtin_amdgcn_sched_barrier(0);
    const unsigned short* buf = &lds[(t % 3) * 12288];
    bf16x8 a[4], b[4];
#pragma unroll
    for (int m = 0; m < 4; ++m)
      a[m] = *(const bf16x8*)&buf[(wm * 64 + m * 16 + lr) * 32 + axr];
#pragma unroll
    for (int n = 0; n < 4; ++n)
      b[n] = *(const bf16x8*)&buf[512 * 8 + (wn * 64 + n * 16 + lr) * 32 + axr];
    STAGE(t + 2);
    __builtin_amdgcn_s_setprio(1);
#pragma unroll
    for (int m = 0; m < 4; ++m)
#pragma unroll
      for (int n = 0; n < 4; ++n)
        acc[m][n] =
            __builtin_amdgcn_mfma_f32_16x16x32_bf16(a[m], b[n], acc[m][n], 0, 0, 0);
    __builtin_amdgcn_s_setprio(0);
  }

  float bv[4];
#pragma unroll
  for (int n = 0; n < 4; ++n) bv[n] = bias[bcol + wn * 64 + n * 16 + lr];

  if (!w2) {
#pragma unroll
    for (int m = 0; m < 4; ++m) {
#pragma unroll
      for (int r = 0; r < 4; ++r) {
        long e = brow + wm * 64 + m * 16 + lh * 4 + r;
#pragma unroll
        for (int n = 0; n < 4; ++n) {
          int oc = bcol + wn * 64 + n * 16 + lr;
          float v = acc[m][n][r] + bv[n];
          if (G.outF) __builtin_nontemporal_store(v, &G.outF[e * Nc + oc]);
          if (outA) outA[e * Nc + oc] = f2bf(fmaxf(v, 0.f));
        }
      }
    }
  } else {
    float w2v[4];
#pragma unroll
    for (int n = 0; n < 4; ++n) w2v[n] = bf2f(w2[wn * 64 + n * 16 + lr]);
#pragma unroll
    for (int m = 0; m < 4; ++m) {
#pragma unroll
      for (int r = 0; r < 4; ++r) {
        float s = 0.f;
#pragma unroll
        for (int n = 0; n < 4; ++n)
          s += fmaxf(acc[m][n][r] + bv[n], 0.f) * w2v[n];
#pragma unroll
        for (int off = 1; off < 16; off <<= 1) s += __shfl_xor(s, off);
        if (lr == 0) part[wn * 128 + wm * 64 + m * 16 + lh * 4 + r] = s;
      }
    }
    __syncthreads();
    if (tid < 128) {
      const int posL = (int)brow + tid;
      if (posL < cpz) {
        float logit = part[tid] + part[128 + tid] + part[256 + tid] +
                      part[384 + tid] + G.Sb2v[z];
        float s = 1.f / (1.f + expf(-logit));
        s = fmaxf(s, 1e-9f);
        float rr = (1.f - s) / s;
        const long orig = (long)G.r0 + G.invIdx[(long)z * NE + G.r0 + posL];
        G.goR[(long)z * NE + orig] = rr;
        G.goS[(long)z * NE + orig] = s;
        G.goM[(long)z * NE + orig] = 1.f;
      }
    }
  }
}

// Dual-stage dispatch: blocks [0, nA) run stage A, [nA, nA+nB) run stage B.
// A and B are INDEPENDENT stages of adjacent chunks (software-pipelined
// chunk loop): shares one launch/ramp/drain instead of two.
__global__ __launch_bounds__(512, 4) void gemmT2(GArgs ga, GArgs gb, int nA) {
  __shared__ unsigned short lds[3 * 12288];
  __shared__ float part[512];
  const int bid = blockIdx.x;
  if (bid < nA) {
    const int bx = bid % ga.gx;
    const int t = bid / ga.gx;
    gemm_body(lds, part, bx, t % ga.gy, t / ga.gy, ga);
  } else {
    const int id = bid - nA;
    const int bx = id % gb.gx;
    const int t = id / gb.gx;
    gemm_body(lds, part, bx, t % gb.gy, t / gb.gy, gb);
  }
}

extern "C" void kernel_launch(void* const* d_in, const int* in_sizes, int n_in,
                              void* d_out, int out_size, void* d_ws, size_t ws_size,
                              hipStream_t stream) {
  const float* x   = (const float*)d_in[0];
  const int*   y   = (const int*)d_in[1];
  const int*   prs = (const int*)d_in[2];
  const float* W0  = (const float*)d_in[3];
  const float* b0  = (const float*)d_in[4];
  const float* W1  = (const float*)d_in[5];
  const float* b1  = (const float*)d_in[6];
  const float* W2  = (const float*)d_in[7];
  const float* b2  = (const float*)d_in[8];
  const float* SW0 = (const float*)d_in[9];
  const float* Sb0 = (const float*)d_in[10];
  const float* SW1 = (const float*)d_in[11];
  const float* Sb1 = (const float*)d_in[12];
  const float* SW2 = (const float*)d_in[13];
  const float* Sb2 = (const float*)d_in[14];

  uint8_t* ws = (uint8_t*)d_ws;
  size_t off = 0;
  auto take = [&](size_t bytes) -> void* {
    void* ptr = ws + off;
    off = (off + bytes + 255) & ~(size_t)255;
    return ptr;
  };
  unsigned short* W0t  = (unsigned short*)take((size_t)64 * 512 * 2);
  unsigned short* W1t  = (unsigned short*)take((size_t)512 * 512 * 2);
  unsigned short* W2t  = (unsigned short*)take((size_t)512 * 512 * 2);
  unsigned short* SW0t = (unsigned short*)take((size_t)3 * 512 * 512 * 2);
  unsigned short* SW1t = (unsigned short*)take((size_t)3 * 256 * 512 * 2);
  unsigned short* SW2b = (unsigned short*)take((size_t)3 * 256 * 2);
  unsigned short* Xb   = (unsigned short*)take((size_t)NE * 64 * 2);
  int*            idxL = (int*)take((size_t)3 * NE * 4);
  int*            posA = (int*)take((size_t)3 * NE * 4);
  int*            cnts = (int*)take((size_t)64 * 4);

  const long chunk = SBCH;                 // R13-verified L3 optimum
  // double-buffered T0/T1/bufR for cross-chunk pipelining; H3 single
  unsigned short* T0[2], *T1[2], *bufR[2];
  for (int i = 0; i < 2; ++i) {
    T0[i]   = (unsigned short*)take((size_t)chunk * 512 * 2);
    T1[i]   = (unsigned short*)take((size_t)chunk * 512 * 2);
    bufR[i] = (unsigned short*)take((size_t)chunk * 512 * 2);
  }
  unsigned short* H3 = (unsigned short*)take((size_t)3 * chunk * 512 * 2);

  float* out   = (float*)d_out;
  float* outRe = out;
  float* outR  = out + (size_t)NE * 512;
  float* outS  = outR + (size_t)3 * NE;
  float* outM  = outS + (size_t)3 * NE;

  prep_all<<<dim3(256, 14), 256, 0, stream>>>(
      W0, W1, W2, SW0, SW1, SW2, W0t, W1t, W2t, SW0t, SW1t, SW2b,
      (const float4*)x, (ushort4*)Xb, y, prs, idxL, posA, cnts);
  hipMemsetAsync(outR, 0, (size_t)9 * NE * 4, stream);

  // stage builders (R19 parameterization)
  auto base = [&]() {
    GArgs g{};
    g.gx = (int)(chunk / 128); g.gy = 2; g.gz = 1;
    return g;
  };
  auto mkL0 = [&](int c) {
    GArgs g = base();
    g.A = Xb + (long)c * chunk * 64; g.Bt = W0t; g.bias = b0;
    g.outA = T0[c & 1]; g.K = 64; g.Nc = 512;
    return g;
  };
  auto mkL1 = [&](int c) {
    GArgs g = base();
    g.A = T0[c & 1]; g.Bt = W1t; g.bias = b1;
    g.outA = T1[c & 1]; g.K = 512; g.Nc = 512;
    return g;
  };
  auto mkL2 = [&](int c) {
    GArgs g = base();
    g.A = T1[c & 1]; g.Bt = W2t; g.bias = b2;
    g.outF = outRe + (long)c * chunk * 512;
    g.outA = bufR[c & 1]; g.K = 512; g.Nc = 512;
    return g;
  };
  auto mkS0 = [&](int c) {
    GArgs g = base();
    g.A = bufR[c & 1]; g.Bt = SW0t; g.bZ = (long)512 * 512;
    g.bias = Sb0; g.biasZ = 512; g.outA = H3; g.cZ = (long)chunk * 512;
    g.K = 512; g.Nc = 512;
    g.aIdx = idxL + (long)c * chunk; g.aIdxZ = NE; g.cnts = cnts + c * 3;
    g.gz = 3;
    return g;
  };
  auto mkS1 = [&](int c) {
    GArgs g = base();
    g.A = H3; g.aZ = (long)chunk * 512; g.Bt = SW1t; g.bZ = (long)256 * 512;
    g.bias = Sb1; g.biasZ = 256; g.K = 512; g.Nc = 256;
    g.w2 = SW2b; g.w2Z = 256; g.r0 = (int)((long)c * chunk);
    g.cnts = cnts + c * 3; g.Sb2v = Sb2; g.invIdx = idxL;
    g.goR = outR; g.goS = outS; g.goM = outM;
    g.gy = 1; g.gz = 3;
    return g;
  };
  auto one = [&](GArgs a) {
    int nA = a.gx * a.gy * a.gz;
    gemmT2<<<dim3(nA), 512, 0, stream>>>(a, a, nA);
  };
  auto two = [&](GArgs a, GArgs b) {
    int nA = a.gx * a.gy * a.gz, nB = b.gx * b.gy * b.gz;
    gemmT2<<<dim3(nA + nB), 512, 0, stream>>>(a, b, nA);
  };

  // software-pipelined chunk loop (conflict table verified in analysis):
  one(mkL0(0));
  two(mkL1(0), mkL0(1));
  two(mkL2(0), mkL1(1));
  two(mkS0(0), mkL2(1));
  two(mkS1(0), mkL0(2));
  two(mkS0(1), mkL1(2));
  two(mkS1(1), mkL2(2));
  two(mkS0(2), mkL0(3));
  two(mkS1(2), mkL1(3));
  one(mkL2(3));
  one(mkS0(3));
  one(mkS1(3));
}